// Round 3
// baseline (720.065 us; speedup 1.0000x reference)
//
#include <hip/hip_runtime.h>

#define G_    128
#define NV_   32
#define EPG_  64
#define LEPG_ 256
#define NG_   (G_*NV_)      // 4096
#define NLG_  (G_*EPG_)     // 8192
#define ELG_  (G_*LEPG_)    // 32768
#define K_    64
#define H_    32
#define HF_   128
#define L_    4
#define NC_   12
#define FIN_  16
#define FE_   16
#define NB_   4
#define TILE_ (K_*H_)       // 2048

// XCD-locality swizzle: graph g occupies block ids == g (mod 8)
__device__ __forceinline__ void swz_node(int bid, int& g, int& v, int& n) {
    g = ((bid >> 9) << 3) | (bid & 7);
    v = (bid >> 3) & 63;
    n = (g << 6) | v;
}

// ---------------------------------------------------------------------------
// enc + glob fused
__global__ __launch_bounds__(256) void k_pre(
    const float* __restrict__ xg, const float* __restrict__ Wenc,
    const float* __restrict__ benc,
    const float* __restrict__ ealg, const float* __restrict__ gaw,
    const float* __restrict__ gab,
    const float* __restrict__ xlg, const float* __restrict__ gdw,
    const float* __restrict__ gdb,
    float* __restrict__ h, float* __restrict__ eglob, float* __restrict__ dglob)
{
    int bid = blockIdx.x, t = threadIdx.x;
    if (bid < 512) {
        int gid = bid*256 + t; int nn = gid>>5, ch = gid&31;
        float s = benc[ch];
#pragma unroll
        for (int f = 0; f < FIN_; ++f) s += xg[nn*FIN_+f]*Wenc[f*H_+ch];
        h[gid] = s;
    } else {
        int gid = (bid-512)*256 + t;
        if (gid < ELG_*4) {
            int e = gid>>2, k = gid&3;
            float s = gab[k];
#pragma unroll
            for (int j = 0; j < 4; ++j) s += ealg[e*4+j]*gaw[j*4+k];
            eglob[gid] = s;
        } else {
            int gid2 = gid - ELG_*4;
            int nn = gid2>>2, k = gid2&3;
            float s = gdb[k];
#pragma unroll
            for (int j = 0; j < 4; ++j) s += xlg[nn*4+j]*gdw[j*4+k];
            dglob[gid2] = s;
        }
    }
}

// hm = [h[s], h[d], edge_attr_g, x_lg] @ W_msg + b_msg     [NLG, HF]
__global__ __launch_bounds__(128) void k_msg(
    const float* __restrict__ h, const float* __restrict__ eag,
    const float* __restrict__ xlg, const int* __restrict__ sidx,
    const int* __restrict__ didx, const float* __restrict__ W,
    const float* __restrict__ b, float* __restrict__ hm) {
    __shared__ float in[84];
    int i = blockIdx.x, t = threadIdx.x;
    int s = sidx[i], d = didx[i];
    if (t < 32)       in[t] = h[s*H_ + t];
    else if (t < 64)  in[t] = h[d*H_ + (t-32)];
    else if (t < 80)  in[t] = eag[i*FE_ + (t-64)];
    else if (t < 84)  in[t] = xlg[i*NB_ + (t-80)];
    __syncthreads();
    float o = b[t];
    for (int k = 0; k < 84; ++k) o += in[k] * W[k*HF_ + t];
    hm[i*HF_ + t] = o;
}

// first extract on the one-hot-sparse u
__global__ __launch_bounds__(128) void k_out0(
    const float* __restrict__ hm, const float* __restrict__ l1w,
    const float* __restrict__ l1b, const float* __restrict__ l2w,
    const float* __restrict__ l2b, const float* __restrict__ lnw,
    const float* __restrict__ lnb, float* __restrict__ out_acc) {
    __shared__ float mh[128], o1[128];
    int g = blockIdx.x, t = threadIdx.x;
    float s = 0.f;
    for (int k = 0; k < 64; ++k) s += hm[(g*64+k)*HF_ + t];
    mh[t] = s * (1.f/64.f);
    __syncthreads();
    float o = l1b[t] + l2b[t] + (l1w[t]*(1.f/64.f) + l2w[t]);
    for (int k = 0; k < 128; ++k)
        o += mh[k] * (l1w[(1+k)*HF_ + t]*(1.f/64.f) + l2w[(1+k)*HF_ + t]);
    o1[t] = o;
    __syncthreads();
    float r = lnb[t];
    for (int k = 0; k < 128; ++k) r += o1[k] * lnw[k*HF_ + t];
    out_acc[g*HF_ + t] = o + (r > 0.f ? r : 0.f);
}

// u0 [n][ch][color] + layer-0 cs/diag stats + per-node in-edge masks + bna zero
__global__ __launch_bounds__(256) void k_u0(
    const float* __restrict__ hm, const float* __restrict__ Wi,
    const float* __restrict__ bi, const int* __restrict__ ldst,
    float* __restrict__ u0, float* __restrict__ nst,
    unsigned long long* __restrict__ mskb, float* __restrict__ bna) {
    __shared__ float rv[32];
    int bid = blockIdx.x, t = threadIdx.x;
    int g, v, n; swz_node(bid, g, v, n);
    int cn = v;
    if (bid == 0) bna[t] = 0.f;
    if (t < 32) {
        float s = Wi[t];
        for (int f = 0; f < HF_; ++f) s += hm[n*HF_ + f] * Wi[(1+f)*H_ + t];
        rv[t] = s;
    }
    if (t < 64) {
        int ebase = g << 8;
#pragma unroll
        for (int r = 0; r < 4; ++r) {
            int d = ldst[ebase + (r<<6) + t];
            unsigned long long mk = __ballot(d == n);
            if (t == 0) mskb[n*4 + r] = mk;
        }
    }
    __syncthreads();
#pragma unroll
    for (int k = 0; k < 8; ++k) {
        int idx = t + k*256;
        int ch = idx >> 6, c = idx & 63;
        u0[(size_t)n*TILE_ + idx] = bi[ch] + (c == cn ? rv[ch] : 0.f);
    }
    if (t < 32) {
        nst[n*96 + t]      = 64.f*bi[t] + rv[t];   // colsum
        nst[n*96 + 32 + t] = bi[t] + rv[t];        // diag row
    }
}

// dl + ef for ALL layers in one launch
__global__ __launch_bounds__(256) void k_dlef(
    const float* __restrict__ dgl, const float* __restrict__ egl,
    const float* __restrict__ ldw, const float* __restrict__ ldb,
    const float* __restrict__ law, const float* __restrict__ lab,
    const float* __restrict__ enw, const float* __restrict__ enb,
    float* __restrict__ dlb, float* __restrict__ efb) {
    int bid = blockIdx.x, t = threadIdx.x;
    if (bid < 4096) {
        int gid = bid*256 + t;                 // [l][n][ch], 4*8192*32
        int l = gid >> 18, rem = gid & ((1<<18)-1);
        int n = rem >> 5, ch = rem & 31;
        float s = ldb[l*32 + ch];
#pragma unroll
        for (int j = 0; j < 4; ++j) s += dgl[n*4+j] * ldw[l*128 + j*32 + ch];
        dlb[gid] = s;
    } else {
        __shared__ float el[8][32];
        int p = (bid - 4096)*8 + (t >> 5);     // (l,e) pair, 4*32768
        int ch = t & 31;
        int l = p >> 15, e = p & 32767;
        float s = lab[l*32 + ch];
#pragma unroll
        for (int j = 0; j < 4; ++j) s += egl[e*4+j] * law[l*128 + j*32 + ch];
        el[t>>5][ch] = s;
        __syncthreads();
        float o = enb[l*32 + ch];
        for (int k = 0; k < 32; ++k) o += el[t>>5][k] * enw[l*1024 + k*32 + ch];
        efb[(size_t)l*ELG_*32 + e*32 + ch] = o;
    }
}

// ---------------------------------------------------------------------------
// main per-layer kernel: barrier/LDS-free, inline BN + gt, pipelined edge loop
__global__ __launch_bounds__(256) void k_layer(
    const float* __restrict__ u_in, float* __restrict__ u_out,
    const int* __restrict__ ls, const unsigned long long* __restrict__ mskb,
    const float* __restrict__ bnaP, const float* __restrict__ bngL,
    const float* __restrict__ bnbL, int layer,
    const float* __restrict__ u1w, const float* __restrict__ u2w,
    const float* __restrict__ u3w, const float* __restrict__ u1b,
    const float* __restrict__ u2b, const float* __restrict__ u3b,
    const float* __restrict__ liw, const float* __restrict__ lib,
    const float* __restrict__ ljw, const float* __restrict__ ljb,
    const float* __restrict__ dlp, const float* __restrict__ efp,
    const float* __restrict__ nin, float* __restrict__ nout)
{
    const int bid = blockIdx.x;
    int g, v, n; swz_node(bid, g, v, n);
    const int t = threadIdx.x;
    const int s = t >> 6;
    const int lane = t & 63;
    const int q = lane >> 3, chL = lane & 7;
    const int ch = s*8 + chL;
    const int chi = ch & 3, twb = ch & ~3;
    const int cn = v;
    const int ebase = g << 8;
    const int eoff = (ch << 6) + (q << 3);

    // masks (uniform)
    unsigned long long m0 = mskb[n*4+0], m1 = mskb[n*4+1],
                       m2 = mskb[n*4+2], m3 = mskb[n*4+3];

    // own loads (issue early)
    float uo[8];
    {
        const float4* p4 = (const float4*)(u_in + ((size_t)n << 11) + eoff);
        float4 A = p4[0], B = p4[1];
        uo[0]=A.x;uo[1]=A.y;uo[2]=A.z;uo[3]=A.w;uo[4]=B.x;uo[5]=B.y;uo[6]=B.z;uo[7]=B.w;
    }
    const float dlo = dlp[(n<<5)+ch];
    float ocs[4], odg[4];
    {
        const float* snp = nin + n*96;
#pragma unroll
        for (int mm = 0; mm < 4; ++mm) {
            int bj = twb + (chi^mm); ocs[mm] = snp[bj]; odg[mm] = snp[32+bj];
        }
    }

    // weights + inline BN fold
    float w1m[4], wim[4], wjm[4], aj[4], bjv[4];
    float scc = 1.f, shc = 0.f;
    float C = u1b[ch] + u2b[ch] + u3b[ch];
#pragma unroll
    for (int mm = 0; mm < 4; ++mm) {
        int jj = chi ^ mm; int bj = twb + jj;
        float s_ = 1.f, m_ = 0.f, sh_ = 0.f;
        if (layer != 0) {
            m_ = bnaP[bj] * (1.f/524288.f);
            float v_ = bnaP[32+bj] * (1.f/524288.f) - m_*m_;
            s_ = bngL[bj] * rsqrtf(v_ + 1e-5f);
            sh_ = bnbL[bj] - m_*s_;
        }
        float w1v = u1w[bj*4+chi], w2v = u2w[bj*4+chi], w3v = u3w[bj*4+chi];
        w1m[mm] = w1v * s_;
        wim[mm] = liw[bj*4+chi];
        wjm[mm] = ljw[bj*4+chi];
        aj[mm]  = s_ * w2v * (1.f/64.f);
        bjv[mm] = s_ * w3v;
        C += sh_ * (w1v + w2v + w3v);
        if (mm == 0) { scc = s_; shc = sh_; }
    }
    const float bli = lib[ch], blj = ljb[ch];

    // uniform edge iterator over the 4 masks
    int rr_ = 0; unsigned long long mc = m0;
    auto nexte = [&]() -> int {
        for (;;) {
            if (mc) { int b = __ffsll(mc) - 1; mc &= mc - 1; return ebase + (rr_<<6) + b; }
            ++rr_;
            if (rr_ == 1) mc = m1; else if (rr_ == 2) mc = m2;
            else if (rr_ == 3) mc = m3; else return -1;
        }
    };

    // prefetch edge A (clamped indices; loads always issue)
    int eA = nexte(); int eAc = (eA >= 0) ? eA : ebase; int sA = ls[eAc];
    float4 A0, A1; float dlA, efA; float acs[4], adg[4];
    {
        const float4* p4 = (const float4*)(u_in + ((size_t)sA << 11) + eoff);
        A0 = p4[0]; A1 = p4[1];
        dlA = dlp[(sA<<5)+ch]; efA = efp[(eAc<<5)+ch];
        const float* sp = nin + sA*96;
#pragma unroll
        for (int mm = 0; mm < 4; ++mm) {
            int bj = twb + (chi^mm); acs[mm] = sp[bj]; adg[mm] = sp[32+bj];
        }
    }
    int eB = (eA >= 0) ? nexte() : -1; int eBc = (eB >= 0) ? eB : ebase; int sB = ls[eBc];

    // own um -> ui (overlaps edge-A gather)
    float ui_[8];
    {
        float gto = C + aj[0]*ocs[0]+aj[1]*ocs[1]+aj[2]*ocs[2]+aj[3]*ocs[3]
                      + bjv[0]*odg[0]+bjv[1]*odg[1]+bjv[2]*odg[2]+bjv[3]*odg[3];
        float gtdlo = gto * dlo;
#pragma unroll
        for (int j = 0; j < 8; ++j) {
            float v1=__shfl_xor(uo[j],1), v2=__shfl_xor(uo[j],2), v3=__shfl_xor(uo[j],3);
            float um = (uo[j]*w1m[0]+v1*w1m[1]+v2*w1m[2]+v3*w1m[3])*dlo + gtdlo;
            float n1=__shfl_xor(um,1), n2=__shfl_xor(um,2), n3=__shfl_xor(um,3);
            ui_[j] = bli + um*wim[0]+n1*wim[1]+n2*wim[2]+n3*wim[3];
        }
    }

    float acc[8];
#pragma unroll
    for (int j = 0; j < 8; ++j) acc[j] = 0.f;

    while (eA >= 0) {
        // prefetch edge B while computing edge A
        int eC = (eB >= 0) ? nexte() : -1; int eCc = (eC >= 0) ? eC : ebase;
        int sC = ls[eCc];
        float4 B0, B1; float dlB, efB; float bcs[4], bdg[4];
        {
            const float4* p4 = (const float4*)(u_in + ((size_t)sB << 11) + eoff);
            B0 = p4[0]; B1 = p4[1];
            dlB = dlp[(sB<<5)+ch]; efB = efp[(eBc<<5)+ch];
            const float* sp = nin + sB*96;
#pragma unroll
            for (int mm = 0; mm < 4; ++mm) {
                int bj = twb + (chi^mm); bcs[mm] = sp[bj]; bdg[mm] = sp[32+bj];
            }
        }
        {
            float gts = C + aj[0]*acs[0]+aj[1]*acs[1]+aj[2]*acs[2]+aj[3]*acs[3]
                          + bjv[0]*adg[0]+bjv[1]*adg[1]+bjv[2]*adg[2]+bjv[3]*adg[3];
            float gtdl = gts * dlA;
            float us[8] = {A0.x,A0.y,A0.z,A0.w,A1.x,A1.y,A1.z,A1.w};
#pragma unroll
            for (int j = 0; j < 8; ++j) {
                float v1=__shfl_xor(us[j],1), v2=__shfl_xor(us[j],2), v3=__shfl_xor(us[j],3);
                float um = (us[j]*w1m[0]+v1*w1m[1]+v2*w1m[2]+v3*w1m[3])*dlA + gtdl;
                float n1=__shfl_xor(um,1), n2=__shfl_xor(um,2), n3=__shfl_xor(um,3);
                float uj = blj + um*wjm[0]+n1*wjm[1]+n2*wjm[2]+n3*wjm[3];
                float rr2 = ui_[j] + uj + efA;
                acc[j] += um + (rr2 > 0.f ? rr2 : 0.f);
            }
        }
        eA = eB; sA = sB; A0 = B0; A1 = B1; dlA = dlB; efA = efB;
#pragma unroll
        for (int mm = 0; mm < 4; ++mm) { acs[mm] = bcs[mm]; adg[mm] = bdg[mm]; }
        eB = eC; eBc = eCc; sB = sC;
    }

    // update + stats (avg_e == 4 exactly by construction)
    float un[8], csum = 0.f, ssum = 0.f;
#pragma unroll
    for (int j = 0; j < 8; ++j) {
        un[j] = acc[j]*0.25f + (scc*uo[j] + shc);
        csum += un[j];
        ssum += un[j]*un[j];
    }
    {
        float4 A = make_float4(un[0],un[1],un[2],un[3]);
        float4 B = make_float4(un[4],un[5],un[6],un[7]);
        float4* p4 = (float4*)(u_out + ((size_t)n << 11) + eoff);
        p4[0] = A; p4[1] = B;
    }
    csum += __shfl_xor(csum, 8);  ssum += __shfl_xor(ssum, 8);
    csum += __shfl_xor(csum, 16); ssum += __shfl_xor(ssum, 16);
    csum += __shfl_xor(csum, 32); ssum += __shfl_xor(ssum, 32);
    if (q == 0) {
        nout[n*96 + ch]      = csum;
        nout[n*96 + 64 + ch] = ssum;
    }
    if (q == (cn >> 3)) {
        float dv;
        switch (cn & 7) {
            case 0: dv = un[0]; break; case 1: dv = un[1]; break;
            case 2: dv = un[2]; break; case 3: dv = un[3]; break;
            case 4: dv = un[4]; break; case 5: dv = un[5]; break;
            case 6: dv = un[6]; break; default: dv = un[7]; break;
        }
        nout[n*96 + 32 + ch] = dv;
    }
}

// extract (per-graph) + bn partial accumulation
__global__ __launch_bounds__(256) void k_extract(
    const float* __restrict__ nst,
    const float* __restrict__ l1w, const float* __restrict__ l1b,
    const float* __restrict__ l2w, const float* __restrict__ l2b,
    const float* __restrict__ lnw, const float* __restrict__ lnb,
    float* __restrict__ out_acc, float* __restrict__ bn_acc, float scale) {
    __shared__ float red[192];
    __shared__ float S[32], D[32], o1[128];
    int g = blockIdx.x, t = threadIdx.x;
    if (t < 192) {
        int half = t / 96, slot = t % 96;
        float s = 0.f;
        const float* p = nst + (size_t)(g*64 + half*32)*96 + slot;
        for (int k = 0; k < 32; ++k) s += p[k*96];
        red[t] = s;
    }
    __syncthreads();
    if (t < 96) {
        float s = red[t] + red[96 + t];
        if (t < 32)      { S[t] = s; atomicAdd(&bn_acc[t], s); }
        else if (t < 64) { D[t-32] = s; }
        else             { atomicAdd(&bn_acc[t-32], s); }
    }
    __syncthreads();
    float o = 0.f;
    if (t < 128) {
        o = l1b[t] + l2b[t];
        for (int k = 0; k < 32; ++k)
            o += (S[k]*(1.f/4096.f))*l1w[k*HF_ + t] + (D[k]*(1.f/64.f))*l2w[k*HF_ + t];
        o1[t] = o;
    }
    __syncthreads();
    if (t < 128) {
        float r = lnb[t];
        for (int k = 0; k < 128; ++k) r += o1[k] * lnw[k*HF_ + t];
        out_acc[g*HF_ + t] += (o + (r > 0.f ? r : 0.f)) * scale;
    }
}

__global__ __launch_bounds__(128) void k_final(
    const float* __restrict__ out_acc, const float* __restrict__ acw,
    const float* __restrict__ acb, const float* __restrict__ flw,
    const float* __restrict__ flb, float* __restrict__ out) {
    __shared__ float t1[128];
    int g = blockIdx.x, t = threadIdx.x;
    float o = out_acc[g*HF_ + t];
    float r = acb[t];
    for (int k = 0; k < 128; ++k) r += out_acc[g*HF_ + k] * acw[k*HF_ + t];
    t1[t] = o + (r > 0.f ? r : 0.f);
    __syncthreads();
    if (t < NC_) {
        float s = flb[t];
        for (int k = 0; k < 128; ++k) s += t1[k] * flw[k*NC_ + t];
        out[g*NC_ + t] = s;
    }
}

// ---------------------------------------------------------------------------
extern "C" void kernel_launch(void* const* d_in, const int* in_sizes, int n_in,
                              void* d_out, int out_size, void* d_ws, size_t ws_size,
                              hipStream_t stream) {
    const float* x_g      = (const float*)d_in[0];
    const float* eag      = (const float*)d_in[1];
    const float* x_lg     = (const float*)d_in[2];
    const float* ealg     = (const float*)d_in[3];
    const float* W_enc    = (const float*)d_in[4];
    const float* b_enc    = (const float*)d_in[5];
    const float* W_msg    = (const float*)d_in[6];
    const float* b_msg    = (const float*)d_in[7];
    const float* W_init   = (const float*)d_in[8];
    const float* b_init   = (const float*)d_in[9];
    const float* np_l1_w  = (const float*)d_in[10];
    const float* np_l1_b  = (const float*)d_in[11];
    const float* np_l2_w  = (const float*)d_in[12];
    const float* np_l2_b  = (const float*)d_in[13];
    const float* np_lin_w = (const float*)d_in[14];
    const float* np_lin_b = (const float*)d_in[15];
    const float* fe_l1_w  = (const float*)d_in[16];
    const float* fe_l1_b  = (const float*)d_in[17];
    const float* fe_l2_w  = (const float*)d_in[18];
    const float* fe_l2_b  = (const float*)d_in[19];
    const float* fe_lin_w = (const float*)d_in[20];
    const float* fe_lin_b = (const float*)d_in[21];
    const float* gd_w     = (const float*)d_in[22];
    const float* gd_b     = (const float*)d_in[23];
    const float* ga_w     = (const float*)d_in[24];
    const float* ga_b     = (const float*)d_in[25];
    const float* ld_w     = (const float*)d_in[26];
    const float* ld_b     = (const float*)d_in[27];
    const float* la_w     = (const float*)d_in[28];
    const float* la_b     = (const float*)d_in[29];
    const float* u1_w     = (const float*)d_in[30];
    const float* u1_b     = (const float*)d_in[31];
    const float* u2_w     = (const float*)d_in[32];
    const float* u2_b     = (const float*)d_in[33];
    const float* u3_w     = (const float*)d_in[34];
    const float* u3_b     = (const float*)d_in[35];
    const float* en_w     = (const float*)d_in[36];
    const float* en_b     = (const float*)d_in[37];
    const float* li_w     = (const float*)d_in[38];
    const float* li_b     = (const float*)d_in[39];
    const float* lj_w     = (const float*)d_in[40];
    const float* lj_b     = (const float*)d_in[41];
    const float* bn_g     = (const float*)d_in[42];
    const float* bn_b     = (const float*)d_in[43];
    const float* ac_w     = (const float*)d_in[44];
    const float* ac_b     = (const float*)d_in[45];
    const float* fl_w     = (const float*)d_in[46];
    const float* fl_b     = (const float*)d_in[47];
    const int*   ei_g     = (const int*)d_in[48];
    const int*   ei_lg    = (const int*)d_in[49];

    const int* s_g  = ei_g;
    const int* d_g  = ei_g + NLG_;
    const int* ls   = ei_lg;
    const int* ldst = ei_lg + ELG_;

    float* ws = (float*)d_ws;
    size_t o = 0;
    unsigned long long* mskb = (unsigned long long*)ws; o += NLG_ * 4 * 2;  // 8B each
    float* ub0  = ws + o; o += (size_t)NLG_ * TILE_;
    float* ub1  = ws + o; o += (size_t)NLG_ * TILE_;
    float* hm   = ws + o; o += (size_t)NLG_ * HF_;
    float* hbuf = ws + o; o += (size_t)NG_ * H_;
    float* dgl  = ws + o; o += (size_t)NLG_ * NB_;
    float* egl  = ws + o; o += (size_t)ELG_ * NB_;
    float* nstA = ws + o; o += (size_t)NLG_ * 96;
    float* nstB = ws + o; o += (size_t)NLG_ * 96;
    float* oac  = ws + o; o += (size_t)G_ * HF_;
    float* bna  = ws + o; o += 256;
    float* dlb  = ws + o; o += (size_t)L_ * NLG_ * 32;
    float* efb  = ws + o; o += (size_t)L_ * ELG_ * 32;

    k_pre<<<1152, 256, 0, stream>>>(x_g, W_enc, b_enc, ealg, ga_w, ga_b,
                                    x_lg, gd_w, gd_b, hbuf, egl, dgl);
    k_msg<<<NLG_, 128, 0, stream>>>(hbuf, eag, x_lg, s_g, d_g, W_msg, b_msg, hm);
    k_dlef<<<4096 + 16384, 256, 0, stream>>>(dgl, egl, ld_w, ld_b, la_w, la_b,
                                             en_w, en_b, dlb, efb);
    k_out0<<<G_, 128, 0, stream>>>(hm, np_l1_w, np_l1_b, np_l2_w, np_l2_b,
                                   np_lin_w, np_lin_b, oac);
    k_u0<<<NLG_, 256, 0, stream>>>(hm, W_init, b_init, ldst, ub0, nstA, mskb, bna);

    float* ubufs[2] = {ub0, ub1};
    float* nbufs[2] = {nstA, nstB};
    for (int i = 0; i < L_; ++i) {
        const float* ui = ubufs[i & 1];
        float* uo = ubufs[(i + 1) & 1];
        const float* ni = nbufs[i & 1];
        float* no = nbufs[(i + 1) & 1];
        k_layer<<<NLG_, 256, 0, stream>>>(
            ui, uo, ls, mskb,
            bna + (i > 0 ? (i-1)*64 : 0), bn_g + i*32, bn_b + i*32, i,
            u1_w + i*128, u2_w + i*128, u3_w + i*128,
            u1_b + i*32, u2_b + i*32, u3_b + i*32,
            li_w + i*128, li_b + i*32,
            lj_w + i*128, lj_b + i*32,
            dlb + (size_t)i*NLG_*32, efb + (size_t)i*ELG_*32,
            ni, no);
        k_extract<<<G_, 256, 0, stream>>>(
            no, fe_l1_w, fe_l1_b, fe_l2_w, fe_l2_b, fe_lin_w, fe_lin_b,
            oac, bna + i*64, 1.0f / (float)L_);
    }
    k_final<<<G_, 128, 0, stream>>>(oac, ac_w, ac_b, fl_w, fl_b, (float*)d_out);
}

// Round 4
// 571.508 us; speedup vs baseline: 1.2599x; 1.2599x over previous
//
#include <hip/hip_runtime.h>

#define G_    128
#define NV_   32
#define EPG_  64
#define LEPG_ 256
#define NG_   (G_*NV_)      // 4096
#define NLG_  (G_*EPG_)     // 8192
#define ELG_  (G_*LEPG_)    // 32768
#define K_    64
#define H_    32
#define HF_   128
#define L_    4
#define NC_   12
#define FIN_  16
#define FE_   16
#define NB_   4
#define TILE_ (K_*H_)       // 2048

// ---------------------------------------------------------------------------
__global__ void k_init(float* bna) {
    int t = threadIdx.x;
    if (t < 256) bna[t] = 0.f;
}

// enc + glob fused (unchanged from round 3)
__global__ __launch_bounds__(256) void k_pre(
    const float* __restrict__ xg, const float* __restrict__ Wenc,
    const float* __restrict__ benc,
    const float* __restrict__ ealg, const float* __restrict__ gaw,
    const float* __restrict__ gab,
    const float* __restrict__ xlg, const float* __restrict__ gdw,
    const float* __restrict__ gdb,
    float* __restrict__ h, float* __restrict__ eglob, float* __restrict__ dglob)
{
    int bid = blockIdx.x, t = threadIdx.x;
    if (bid < 512) {
        int gid = bid*256 + t; int nn = gid>>5, ch = gid&31;
        float s = benc[ch];
#pragma unroll
        for (int f = 0; f < FIN_; ++f) s += xg[nn*FIN_+f]*Wenc[f*H_+ch];
        h[gid] = s;
    } else {
        int gid = (bid-512)*256 + t;
        if (gid < ELG_*4) {
            int e = gid>>2, k = gid&3;
            float s = gab[k];
#pragma unroll
            for (int j = 0; j < 4; ++j) s += ealg[e*4+j]*gaw[j*4+k];
            eglob[gid] = s;
        } else {
            int gid2 = gid - ELG_*4;
            int nn = gid2>>2, k = gid2&3;
            float s = gdb[k];
#pragma unroll
            for (int j = 0; j < 4; ++j) s += xlg[nn*4+j]*gdw[j*4+k];
            dglob[gid2] = s;
        }
    }
}

// p1[n][o] = h[n] @ Wmsg[0:32], p2 = h[n] @ Wmsg[32:64]
__global__ __launch_bounds__(256) void k_p12(
    const float* __restrict__ h, const float* __restrict__ Wm,
    float* __restrict__ p1, float* __restrict__ p2) {
    int bid = blockIdx.x, t = threadIdx.x;
    int n = bid*2 + (t>>7), o = t&127;
    const float* hn = h + n*32;
    float a = 0.f, b = 0.f;
#pragma unroll
    for (int k = 0; k < 32; ++k) {
        float hv = hn[k];
        a += hv * Wm[k*HF_ + o];
        b += hv * Wm[(32+k)*HF_ + o];
    }
    p1[n*HF_ + o] = a; p2[n*HF_ + o] = b;
}

// q34[e][o] = b_msg[o] + eag[e]@Wmsg[64:80] + xlg[e]@Wmsg[80:84]
__global__ __launch_bounds__(256) void k_q34(
    const float* __restrict__ eag, const float* __restrict__ xlg,
    const float* __restrict__ Wm, const float* __restrict__ bm,
    float* __restrict__ q34) {
    int bid = blockIdx.x, t = threadIdx.x;
    int e = bid*2 + (t>>7), o = t&127;
    float s = bm[o];
#pragma unroll
    for (int k = 0; k < 16; ++k) s += eag[e*16+k] * Wm[(64+k)*HF_ + o];
#pragma unroll
    for (int k = 0; k < 4; ++k)  s += xlg[e*4+k]  * Wm[(80+k)*HF_ + o];
    q34[e*HF_ + o] = s;
}

// hm[e] = p1[s] + p2[d] + q34[e]
__global__ __launch_bounds__(256) void k_msg2(
    const float* __restrict__ p1, const float* __restrict__ p2,
    const float* __restrict__ q34, const int* __restrict__ sidx,
    const int* __restrict__ didx, float* __restrict__ hm) {
    int idx = blockIdx.x*256 + threadIdx.x;     // NLG*32 float4s
    int e = idx >> 5, o4 = idx & 31;
    int s = sidx[e], d = didx[e];
    float4 a = ((const float4*)p1)[s*32 + o4];
    float4 b = ((const float4*)p2)[d*32 + o4];
    float4 q = ((const float4*)q34)[e*32 + o4];
    ((float4*)hm)[idx] = make_float4(a.x+b.x+q.x, a.y+b.y+q.y, a.z+b.z+q.z, a.w+b.w+q.w);
}

// first extract on the one-hot-sparse u (unchanged)
__global__ __launch_bounds__(128) void k_out0(
    const float* __restrict__ hm, const float* __restrict__ l1w,
    const float* __restrict__ l1b, const float* __restrict__ l2w,
    const float* __restrict__ l2b, const float* __restrict__ lnw,
    const float* __restrict__ lnb, float* __restrict__ out_acc) {
    __shared__ float mh[128], o1[128];
    int g = blockIdx.x, t = threadIdx.x;
    float s = 0.f;
    for (int k = 0; k < 64; ++k) s += hm[(g*64+k)*HF_ + t];
    mh[t] = s * (1.f/64.f);
    __syncthreads();
    float o = l1b[t] + l2b[t] + (l1w[t]*(1.f/64.f) + l2w[t]);
    for (int k = 0; k < 128; ++k)
        o += mh[k] * (l1w[(1+k)*HF_ + t]*(1.f/64.f) + l2w[(1+k)*HF_ + t]);
    o1[t] = o;
    __syncthreads();
    float r = lnb[t];
    for (int k = 0; k < 128; ++k) r += o1[k] * lnw[k*HF_ + t];
    out_acc[g*HF_ + t] = o + (r > 0.f ? r : 0.f);
}

// rv = W_init[0] + hm @ W_init[1:] ; layer-0 stats cs0/ds0
__global__ __launch_bounds__(256) void k_rv(
    const float* __restrict__ hm, const float* __restrict__ Wi,
    const float* __restrict__ bi, float* __restrict__ rv,
    float* __restrict__ cs, float* __restrict__ ds) {
    int bid = blockIdx.x, t = threadIdx.x;
    int n = bid*8 + (t>>5), ch = t&31;
    float s = Wi[ch];
    for (int f = 0; f < HF_; ++f) s += hm[n*HF_ + f] * Wi[(1+f)*H_ + ch];
    rv[n*32 + ch] = s;
    cs[n*32 + ch] = 64.f*bi[ch] + s;
    ds[n*32 + ch] = bi[ch] + s;
}

// u0 writer: [n][color][ch], u0 = bi + (c==n%64)*rv[n]
__global__ __launch_bounds__(256) void k_u0w(
    const float* __restrict__ rv, const float* __restrict__ bi,
    float* __restrict__ u0) {
    int bid = blockIdx.x, t = threadIdx.x;
    int c4 = t & 7;
    float4 b4 = ((const float4*)bi)[c4];
#pragma unroll
    for (int k = 0; k < 8; ++k) {
        int lin = bid*2048 + k*256 + t;           // float4 index
        int n = lin >> 9, c = (lin >> 3) & 63;
        float4 v = b4;
        if (c == (n & 63)) {
            float4 r = ((const float4*)rv)[n*8 + c4];
            v.x += r.x; v.y += r.y; v.z += r.z; v.w += r.w;
        }
        ((float4*)u0)[lin] = v;
    }
}

// per-graph in-edge CSR
__global__ __launch_bounds__(256) void k_csr(
    const int* __restrict__ ls, const int* __restrict__ ld,
    int* __restrict__ offsg, int* __restrict__ csrp) {
    __shared__ int cnt[64], offs[65], cur[64];
    int g = blockIdx.x, t = threadIdx.x;
    if (t < 64) cnt[t] = 0;
    __syncthreads();
    int d = 0, sl = 0;
    d = ld[g*256 + t] & 63;
    sl = ls[g*256 + t] & 63;
    atomicAdd(&cnt[d], 1);
    __syncthreads();
    if (t == 0) {
        int a = 0;
        for (int i = 0; i < 64; ++i) { offs[i] = a; a += cnt[i]; }
        offs[64] = a;
    }
    __syncthreads();
    if (t < 64) { cur[t] = offs[t]; offsg[g*65 + t] = offs[t]; }
    if (t == 0) offsg[g*65 + 64] = offs[64];
    __syncthreads();
    int p = atomicAdd(&cur[d], 1);
    csrp[g*256 + p] = (t << 6) | sl;
}

// dl + ef for ALL layers (unchanged from round 3)
__global__ __launch_bounds__(256) void k_dlef(
    const float* __restrict__ dgl, const float* __restrict__ egl,
    const float* __restrict__ ldw, const float* __restrict__ ldb,
    const float* __restrict__ law, const float* __restrict__ lab,
    const float* __restrict__ enw, const float* __restrict__ enb,
    float* __restrict__ dlb, float* __restrict__ efb) {
    int bid = blockIdx.x, t = threadIdx.x;
    if (bid < 4096) {
        int gid = bid*256 + t;
        int l = gid >> 18, rem = gid & ((1<<18)-1);
        int n = rem >> 5, ch = rem & 31;
        float s = ldb[l*32 + ch];
#pragma unroll
        for (int j = 0; j < 4; ++j) s += dgl[n*4+j] * ldw[l*128 + j*32 + ch];
        dlb[gid] = s;
    } else {
        __shared__ float el[8][32];
        int p = (bid - 4096)*8 + (t >> 5);
        int ch = t & 31;
        int l = p >> 15, e = p & 32767;
        float s = lab[l*32 + ch];
#pragma unroll
        for (int j = 0; j < 4; ++j) s += egl[e*4+j] * law[l*128 + j*32 + ch];
        el[t>>5][ch] = s;
        __syncthreads();
        float o = enb[l*32 + ch];
        for (int k = 0; k < 32; ++k) o += el[t>>5][k] * enw[l*1024 + k*32 + ch];
        efb[(size_t)l*ELG_*32 + e*32 + ch] = o;
    }
}

// gtdl[n][ch] for one layer (BN fold inline from bna)
__global__ __launch_bounds__(256) void k_gtdl(
    const float* __restrict__ cs, const float* __restrict__ ds,
    const float* __restrict__ bnaP, const float* __restrict__ bng,
    const float* __restrict__ bnb, int lay,
    const float* __restrict__ u1w, const float* __restrict__ u2w,
    const float* __restrict__ u3w, const float* __restrict__ u1b,
    const float* __restrict__ u2b, const float* __restrict__ u3b,
    const float* __restrict__ dl_l, float* __restrict__ gtb) {
    int idx = blockIdx.x*256 + threadIdx.x;
    int n = idx >> 5, ch = idx & 31;
    int chi = ch & 3, twb = ch & ~3;
    float gt = u1b[ch] + u2b[ch] + u3b[ch];
#pragma unroll
    for (int j = 0; j < 4; ++j) {
        int bj = twb + j;
        float s_ = 1.f, sh_ = 0.f;
        if (lay > 0) {
            float m = bnaP[bj] * (1.f/524288.f);
            float v = bnaP[32+bj] * (1.f/524288.f) - m*m;
            s_ = bng[bj] * rsqrtf(v + 1e-5f);
            sh_ = bnb[bj] - m*s_;
        }
        float csF = s_*cs[n*32 + bj] + 64.f*sh_;
        float dgF = s_*ds[n*32 + bj] + sh_;
        gt += csF*(1.f/64.f)*u2w[bj*4 + chi] + dgF*u3w[bj*4 + chi]
            + sh_*u1w[bj*4 + chi];
    }
    gtb[idx] = gt * dl_l[idx];
}

// ---------------------------------------------------------------------------
// main layer kernel: block = (graph, 4-color chunk); edges served from LDS
#define PROC_NODE(ACC, UI, JE)                                              \
  for (; j < (JE); ++j) {                                                   \
    int jn = j + 2; jn = jn < 255 ? jn : 255;                               \
    int pkN = ep[jn];                                                       \
    float4 efN = *(const float4*)(ef_l + (((size_t)((g<<8)+(pkN>>6)))<<5) + chb); \
    int src = pkA & 63;                                                     \
    float4 u4 = *(float4*)&um[src*128 + coff];                              \
    float r0 = UI.x + efA.x + blj4[0] + u4.x*wj[0] + u4.y*wj[4] + u4.z*wj[8] + u4.w*wj[12]; \
    float r1 = UI.y + efA.y + blj4[1] + u4.x*wj[1] + u4.y*wj[5] + u4.z*wj[9] + u4.w*wj[13]; \
    float r2 = UI.z + efA.z + blj4[2] + u4.x*wj[2] + u4.y*wj[6] + u4.z*wj[10] + u4.w*wj[14]; \
    float r3 = UI.w + efA.w + blj4[3] + u4.x*wj[3] + u4.y*wj[7] + u4.z*wj[11] + u4.w*wj[15]; \
    ACC.x += u4.x + (r0>0.f?r0:0.f);                                        \
    ACC.y += u4.y + (r1>0.f?r1:0.f);                                        \
    ACC.z += u4.z + (r2>0.f?r2:0.f);                                        \
    ACC.w += u4.w + (r3>0.f?r3:0.f);                                        \
    pkA = pkB; efA = efB; pkB = pkN; efB = efN;                             \
  }

#define UM_NODE(I, UIOUT, DL, GT)                                           \
  {                                                                         \
    int nl = nq*4 + I;                                                      \
    float4 uv = *(float4*)&us[nl*128 + coff];                               \
    float m0 = (uv.x*w1f[0]+uv.y*w1f[4]+uv.z*w1f[8] +uv.w*w1f[12])*DL.x + GT.x; \
    float m1 = (uv.x*w1f[1]+uv.y*w1f[5]+uv.z*w1f[9] +uv.w*w1f[13])*DL.y + GT.y; \
    float m2 = (uv.x*w1f[2]+uv.y*w1f[6]+uv.z*w1f[10]+uv.w*w1f[14])*DL.z + GT.z; \
    float m3 = (uv.x*w1f[3]+uv.y*w1f[7]+uv.z*w1f[11]+uv.w*w1f[15])*DL.w + GT.w; \
    *(float4*)&um[nl*128 + coff] = make_float4(m0,m1,m2,m3);                \
    UIOUT.x = bli4[0] + m0*wi[0] + m1*wi[4] + m2*wi[8]  + m3*wi[12];        \
    UIOUT.y = bli4[1] + m0*wi[1] + m1*wi[5] + m2*wi[9]  + m3*wi[13];        \
    UIOUT.z = bli4[2] + m0*wi[2] + m1*wi[6] + m2*wi[10] + m3*wi[14];        \
    UIOUT.w = bli4[3] + m0*wi[3] + m1*wi[7] + m2*wi[11] + m3*wi[15];        \
  }

#define UN_NODE(I, ACC)                                                     \
  {                                                                         \
    float4 uo4 = *(float4*)&us[(nq*4+I)*128 + coff];                        \
    float4 un4;                                                             \
    un4.x = ACC.x*0.25f + sc4[0]*uo4.x + sh4[0];                            \
    un4.y = ACC.y*0.25f + sc4[1]*uo4.y + sh4[1];                            \
    un4.z = ACC.z*0.25f + sc4[2]*uo4.z + sh4[2];                            \
    un4.w = ACC.w*0.25f + sc4[3]*uo4.w + sh4[3];                            \
    *(float4*)(u_out + (((size_t)(n0g+I))<<11) + (ck<<7) + coff) = un4;     \
    if (nq == ck && c == I)                                                 \
        *(float4*)&dsb[(((size_t)(n0g+I))<<5) + chb] = un4;                 \
    float cx=un4.x, cy=un4.y, cz=un4.z, cw=un4.w;                           \
    float qx=cx*cx, qy=cy*cy, qz=cz*cz, qw=cw*cw;                           \
    cx+=__shfl_xor(cx,8);  cy+=__shfl_xor(cy,8);  cz+=__shfl_xor(cz,8);  cw+=__shfl_xor(cw,8); \
    qx+=__shfl_xor(qx,8);  qy+=__shfl_xor(qy,8);  qz+=__shfl_xor(qz,8);  qw+=__shfl_xor(qw,8); \
    cx+=__shfl_xor(cx,16); cy+=__shfl_xor(cy,16); cz+=__shfl_xor(cz,16); cw+=__shfl_xor(cw,16); \
    qx+=__shfl_xor(qx,16); qy+=__shfl_xor(qy,16); qz+=__shfl_xor(qz,16); qw+=__shfl_xor(qw,16); \
    if (c == 0) {                                                           \
        *(float4*)&pcs[(((size_t)(ck*NLG_ + n0g + I))<<5) + chb] = make_float4(cx,cy,cz,cw); \
        *(float4*)&pss[(((size_t)(ck*NLG_ + n0g + I))<<5) + chb] = make_float4(qx,qy,qz,qw); \
    }                                                                       \
  }

__global__ __launch_bounds__(512, 4) void k_layer(
    const float* __restrict__ u_in, float* __restrict__ u_out,
    const int* __restrict__ offsg, const int* __restrict__ csrp,
    const float* __restrict__ bnaP, const float* __restrict__ bng,
    const float* __restrict__ bnb, int lay,
    const float* __restrict__ u1w,
    const float* __restrict__ liw, const float* __restrict__ lib,
    const float* __restrict__ ljw, const float* __restrict__ ljb,
    const float* __restrict__ dl_l, const float* __restrict__ gtb,
    const float* __restrict__ ef_l,
    float* __restrict__ pcs, float* __restrict__ pss, float* __restrict__ dsb)
{
    __shared__ float us[64*128];
    __shared__ float um[64*128];
    __shared__ int ep[256];
    __shared__ int offs[65];

    const int bid = blockIdx.x, t = threadIdx.x;
    const int g  = ((bid >> 7) << 3) | (bid & 7);
    const int ck = (bid >> 3) & 15;
    const int tw = t & 7, c = (t >> 3) & 3, nq = t >> 5;
    const int chb = tw * 4;
    const int coff = c*32 + chb;
    const int n0g = g*64 + nq*4;

    if (t < 256) ep[t] = csrp[g*256 + t];
    else if (t < 256 + 65) offs[t - 256] = offsg[g*65 + (t - 256)];

    // stage u slice (each element read exactly once, coalesced)
    {
        const float* ub = u_in + ((size_t)g << 17) + (ck << 7);
#pragma unroll
        for (int r = 0; r < 4; ++r) {
            int lin = r*2048 + t*4;
            int nl = lin >> 7, off = lin & 127;
            float4 v = *(const float4*)(ub + ((size_t)nl << 11) + off);
            *(float4*)&us[lin] = v;
        }
    }

    // dl/gtdl for owned nodes (L2-hot, issued before barrier)
    float4 dl0 = *(const float4*)(dl_l + (((size_t)(n0g+0))<<5) + chb);
    float4 dl1 = *(const float4*)(dl_l + (((size_t)(n0g+1))<<5) + chb);
    float4 dl2 = *(const float4*)(dl_l + (((size_t)(n0g+2))<<5) + chb);
    float4 dl3 = *(const float4*)(dl_l + (((size_t)(n0g+3))<<5) + chb);
    float4 gt0 = *(const float4*)(gtb + (((size_t)(n0g+0))<<5) + chb);
    float4 gt1 = *(const float4*)(gtb + (((size_t)(n0g+1))<<5) + chb);
    float4 gt2 = *(const float4*)(gtb + (((size_t)(n0g+2))<<5) + chb);
    float4 gt3 = *(const float4*)(gtb + (((size_t)(n0g+3))<<5) + chb);

    // weights + BN fold
    float sc4[4], sh4[4];
    if (lay > 0) {
#pragma unroll
        for (int j = 0; j < 4; ++j) {
            int bj = chb + j;
            float m = bnaP[bj] * (1.f/524288.f);
            float v = bnaP[32+bj] * (1.f/524288.f) - m*m;
            float s_ = bng[bj] * rsqrtf(v + 1e-5f);
            sc4[j] = s_; sh4[j] = bnb[bj] - m*s_;
        }
    } else {
#pragma unroll
        for (int j = 0; j < 4; ++j) { sc4[j] = 1.f; sh4[j] = 0.f; }
    }
    float w1f[16], wi[16], wj[16], bli4[4], blj4[4];
#pragma unroll
    for (int j = 0; j < 4; ++j)
#pragma unroll
        for (int d = 0; d < 4; ++d) {
            w1f[j*4+d] = u1w[(chb+j)*4 + d] * sc4[j];
            wi [j*4+d] = liw[(chb+j)*4 + d];
            wj [j*4+d] = ljw[(chb+j)*4 + d];
        }
#pragma unroll
    for (int d = 0; d < 4; ++d) { bli4[d] = lib[chb+d]; blj4[d] = ljb[chb+d]; }

    __syncthreads();

    // um + ui for owned nodes
    float4 ui0, ui1, ui2, ui3;
    UM_NODE(0, ui0, dl0, gt0)
    UM_NODE(1, ui1, dl1, gt1)
    UM_NODE(2, ui2, dl2, gt2)
    UM_NODE(3, ui3, dl3, gt3)
    __syncthreads();

    // edge aggregation from LDS um
    float4 acc0 = make_float4(0,0,0,0), acc1 = acc0, acc2 = acc0, acc3 = acc0;
    int j = offs[nq*4];
    {
        int ja = j < 255 ? j : 255;
        int pkA = ep[ja];
        float4 efA = *(const float4*)(ef_l + (((size_t)((g<<8)+(pkA>>6)))<<5) + chb);
        int jb = (j+1) < 255 ? (j+1) : 255;
        int pkB = ep[jb];
        float4 efB = *(const float4*)(ef_l + (((size_t)((g<<8)+(pkB>>6)))<<5) + chb);
        int e1 = offs[nq*4+1], e2 = offs[nq*4+2], e3 = offs[nq*4+3], e4 = offs[nq*4+4];
        PROC_NODE(acc0, ui0, e1)
        PROC_NODE(acc1, ui1, e2)
        PROC_NODE(acc2, ui2, e3)
        PROC_NODE(acc3, ui3, e4)
    }

    // update + write + stats
    UN_NODE(0, acc0)
    UN_NODE(1, acc1)
    UN_NODE(2, acc2)
    UN_NODE(3, acc3)
}

// chunk-reduce + bn accumulation + graph extract, per graph
__global__ __launch_bounds__(256) void k_midx(
    const float* __restrict__ pcs, const float* __restrict__ pss,
    const float* __restrict__ dsb,
    const float* __restrict__ l1w, const float* __restrict__ l1b,
    const float* __restrict__ l2w, const float* __restrict__ l2b,
    const float* __restrict__ lnw, const float* __restrict__ lnb,
    float* __restrict__ csb, float* __restrict__ bna_i,
    float* __restrict__ out_acc, float scale)
{
    __shared__ float red[3*128];
    __shared__ float S[32], D[32], o1[128];
    int g = blockIdx.x, t = threadIdx.x;
    int ch = t & 31, ng = t >> 5;
    float pS = 0.f, pQ = 0.f, pD = 0.f;
#pragma unroll
    for (int k = 0; k < 8; ++k) {
        int n = g*64 + ng + 8*k;
        float cs_ = 0.f, ss_ = 0.f;
#pragma unroll
        for (int ckk = 0; ckk < 16; ++ckk) {
            cs_ += pcs[((size_t)ckk*NLG_ + n)*32 + ch];
            ss_ += pss[((size_t)ckk*NLG_ + n)*32 + ch];
        }
        csb[n*32 + ch] = cs_;
        pS += cs_; pQ += ss_;
        pD += dsb[n*32 + ch];
    }
    pS += __shfl_xor(pS, 32); pQ += __shfl_xor(pQ, 32); pD += __shfl_xor(pD, 32);
    int w = t >> 6;
    if ((t & 63) < 32) {
        red[w*32 + ch] = pS;
        red[128 + w*32 + ch] = pQ;
        red[256 + w*32 + ch] = pD;
    }
    __syncthreads();
    if (t < 32) {
        float S_ = 0.f, Q_ = 0.f, D_ = 0.f;
#pragma unroll
        for (int ww = 0; ww < 4; ++ww) {
            S_ += red[ww*32 + t]; Q_ += red[128 + ww*32 + t]; D_ += red[256 + ww*32 + t];
        }
        S[t] = S_; D[t] = D_;
        atomicAdd(&bna_i[t], S_);
        atomicAdd(&bna_i[32 + t], Q_);
    }
    __syncthreads();
    float o = 0.f;
    if (t < 128) {
        o = l1b[t] + l2b[t];
        for (int k = 0; k < 32; ++k)
            o += (S[k]*(1.f/4096.f))*l1w[k*HF_ + t] + (D[k]*(1.f/64.f))*l2w[k*HF_ + t];
        o1[t] = o;
    }
    __syncthreads();
    if (t < 128) {
        float r = lnb[t];
        for (int k = 0; k < 128; ++k) r += o1[k] * lnw[k*HF_ + t];
        out_acc[g*HF_ + t] += (o + (r > 0.f ? r : 0.f)) * scale;
    }
}

__global__ __launch_bounds__(128) void k_final(
    const float* __restrict__ out_acc, const float* __restrict__ acw,
    const float* __restrict__ acb, const float* __restrict__ flw,
    const float* __restrict__ flb, float* __restrict__ out) {
    __shared__ float t1[128];
    int g = blockIdx.x, t = threadIdx.x;
    float o = out_acc[g*HF_ + t];
    float r = acb[t];
    for (int k = 0; k < 128; ++k) r += out_acc[g*HF_ + k] * acw[k*HF_ + t];
    t1[t] = o + (r > 0.f ? r : 0.f);
    __syncthreads();
    if (t < NC_) {
        float s = flb[t];
        for (int k = 0; k < 128; ++k) s += t1[k] * flw[k*NC_ + t];
        out[g*NC_ + t] = s;
    }
}

// ---------------------------------------------------------------------------
extern "C" void kernel_launch(void* const* d_in, const int* in_sizes, int n_in,
                              void* d_out, int out_size, void* d_ws, size_t ws_size,
                              hipStream_t stream) {
    const float* x_g      = (const float*)d_in[0];
    const float* eag      = (const float*)d_in[1];
    const float* x_lg     = (const float*)d_in[2];
    const float* ealg     = (const float*)d_in[3];
    const float* W_enc    = (const float*)d_in[4];
    const float* b_enc    = (const float*)d_in[5];
    const float* W_msg    = (const float*)d_in[6];
    const float* b_msg    = (const float*)d_in[7];
    const float* W_init   = (const float*)d_in[8];
    const float* b_init   = (const float*)d_in[9];
    const float* np_l1_w  = (const float*)d_in[10];
    const float* np_l1_b  = (const float*)d_in[11];
    const float* np_l2_w  = (const float*)d_in[12];
    const float* np_l2_b  = (const float*)d_in[13];
    const float* np_lin_w = (const float*)d_in[14];
    const float* np_lin_b = (const float*)d_in[15];
    const float* fe_l1_w  = (const float*)d_in[16];
    const float* fe_l1_b  = (const float*)d_in[17];
    const float* fe_l2_w  = (const float*)d_in[18];
    const float* fe_l2_b  = (const float*)d_in[19];
    const float* fe_lin_w = (const float*)d_in[20];
    const float* fe_lin_b = (const float*)d_in[21];
    const float* gd_w     = (const float*)d_in[22];
    const float* gd_b     = (const float*)d_in[23];
    const float* ga_w     = (const float*)d_in[24];
    const float* ga_b     = (const float*)d_in[25];
    const float* ld_w     = (const float*)d_in[26];
    const float* ld_b     = (const float*)d_in[27];
    const float* la_w     = (const float*)d_in[28];
    const float* la_b     = (const float*)d_in[29];
    const float* u1_w     = (const float*)d_in[30];
    const float* u1_b     = (const float*)d_in[31];
    const float* u2_w     = (const float*)d_in[32];
    const float* u2_b     = (const float*)d_in[33];
    const float* u3_w     = (const float*)d_in[34];
    const float* u3_b     = (const float*)d_in[35];
    const float* en_w     = (const float*)d_in[36];
    const float* en_b     = (const float*)d_in[37];
    const float* li_w     = (const float*)d_in[38];
    const float* li_b     = (const float*)d_in[39];
    const float* lj_w     = (const float*)d_in[40];
    const float* lj_b     = (const float*)d_in[41];
    const float* bn_g     = (const float*)d_in[42];
    const float* bn_b     = (const float*)d_in[43];
    const float* ac_w     = (const float*)d_in[44];
    const float* ac_b     = (const float*)d_in[45];
    const float* fl_w     = (const float*)d_in[46];
    const float* fl_b     = (const float*)d_in[47];
    const int*   ei_g     = (const int*)d_in[48];
    const int*   ei_lg    = (const int*)d_in[49];

    const int* s_g  = ei_g;
    const int* d_g  = ei_g + NLG_;
    const int* ls   = ei_lg;
    const int* ldst = ei_lg + ELG_;

    float* ws = (float*)d_ws;
    size_t o = 0;
    float* ub0  = ws + o; o += (size_t)NLG_ * TILE_;
    float* ub1  = ws + o; o += (size_t)NLG_ * TILE_;
    float* hm   = ws + o; o += (size_t)NLG_ * HF_;
    float* hbuf = ws + o; o += (size_t)NG_ * H_;
    float* dgl  = ws + o; o += (size_t)NLG_ * NB_;
    float* egl  = ws + o; o += (size_t)ELG_ * NB_;
    float* p1b  = ws + o; o += (size_t)NG_ * HF_;
    float* p2b  = ws + o; o += (size_t)NG_ * HF_;
    float* q34b = ws + o; o += (size_t)NLG_ * HF_;
    float* rvb  = ws + o; o += (size_t)NLG_ * 32;
    float* csb  = ws + o; o += (size_t)NLG_ * 32;
    float* dsb  = ws + o; o += (size_t)NLG_ * 32;
    float* gtb  = ws + o; o += (size_t)NLG_ * 32;
    float* pcs  = ws + o; o += (size_t)16 * NLG_ * 32;
    float* pss  = ws + o; o += (size_t)16 * NLG_ * 32;
    float* oac  = ws + o; o += (size_t)G_ * HF_;
    float* bna  = ws + o; o += 256;
    float* dlb  = ws + o; o += (size_t)L_ * NLG_ * 32;
    float* efb  = ws + o; o += (size_t)L_ * ELG_ * 32;
    int*   offsg = (int*)(ws + o); o += G_ * 65;
    int*   csrp  = (int*)(ws + o); o += ELG_;

    k_init<<<1, 256, 0, stream>>>(bna);
    k_pre<<<1152, 256, 0, stream>>>(x_g, W_enc, b_enc, ealg, ga_w, ga_b,
                                    x_lg, gd_w, gd_b, hbuf, egl, dgl);
    k_p12<<<2048, 256, 0, stream>>>(hbuf, W_msg, p1b, p2b);
    k_q34<<<4096, 256, 0, stream>>>(eag, x_lg, W_msg, b_msg, q34b);
    k_msg2<<<1024, 256, 0, stream>>>(p1b, p2b, q34b, s_g, d_g, hm);
    k_dlef<<<4096 + 16384, 256, 0, stream>>>(dgl, egl, ld_w, ld_b, la_w, la_b,
                                             en_w, en_b, dlb, efb);
    k_out0<<<G_, 128, 0, stream>>>(hm, np_l1_w, np_l1_b, np_l2_w, np_l2_b,
                                   np_lin_w, np_lin_b, oac);
    k_rv<<<1024, 256, 0, stream>>>(hm, W_init, b_init, rvb, csb, dsb);
    k_u0w<<<2048, 256, 0, stream>>>(rvb, b_init, ub0);
    k_csr<<<G_, 256, 0, stream>>>(ls, ldst, offsg, csrp);
    k_gtdl<<<1024, 256, 0, stream>>>(csb, dsb, bna, bn_g, bn_b, 0,
                                     u1_w, u2_w, u3_w, u1_b, u2_b, u3_b,
                                     dlb, gtb);

    float* ubufs[2] = {ub0, ub1};
    for (int i = 0; i < L_; ++i) {
        const float* ui = ubufs[i & 1];
        float* uo = ubufs[(i + 1) & 1];
        k_layer<<<2048, 512, 0, stream>>>(
            ui, uo, offsg, csrp,
            (i > 0 ? bna + (i-1)*64 : bna), bn_g + i*32, bn_b + i*32, i,
            u1_w + i*128,
            li_w + i*128, li_b + i*32,
            lj_w + i*128, lj_b + i*32,
            dlb + (size_t)i*NLG_*32, gtb, efb + (size_t)i*ELG_*32,
            pcs, pss, dsb);
        k_midx<<<G_, 256, 0, stream>>>(
            pcs, pss, dsb,
            fe_l1_w, fe_l1_b, fe_l2_w, fe_l2_b, fe_lin_w, fe_lin_b,
            csb, bna + i*64, oac, 1.0f / (float)L_);
        if (i < L_ - 1)
            k_gtdl<<<1024, 256, 0, stream>>>(csb, dsb, bna + i*64,
                                             bn_g + (i+1)*32, bn_b + (i+1)*32, i+1,
                                             u1_w + (i+1)*128, u2_w + (i+1)*128,
                                             u3_w + (i+1)*128, u1_b + (i+1)*32,
                                             u2_b + (i+1)*32, u3_b + (i+1)*32,
                                             dlb + (size_t)(i+1)*NLG_*32, gtb);
    }
    k_final<<<G_, 128, 0, stream>>>(oac, ac_w, ac_b, fl_w, fl_b, (float*)d_out);
}